// Round 1
// baseline (231.106 us; speedup 1.0000x reference)
//
#include <hip/hip_runtime.h>

// Dense image warp (bilinear), B=8 H=256 W=256 C=64, fp32.
// One thread = TWO float4s (channels quads q and q+8) of one output pixel.
// 8 threads per pixel; output stores are nontemporal (write-once stream),
// keeping L2/L3 capacity for the image gather, which has 2x vertical reuse.
// All addressing 32-bit (max byte offset 2^27).

typedef float f4 __attribute__((ext_vector_type(4)));

__global__ __launch_bounds__(256) void warp_bilinear_kernel(
    const float* __restrict__ image,
    const float* __restrict__ flow,
    float* __restrict__ out)
{
    constexpr int H = 256, W = 256, C = 64;
    constexpr int QUADS = C / 4;       // 16 float4 per pixel
    constexpr int R = W * QUADS;       // float4s per image row = 4096

    const int gid = blockIdx.x * blockDim.x + threadIdx.x;
    const int p = gid >> 3;            // pixel index: b*H*W + y*W + x
    const int q = gid & 7;             // handles quads q and q+8

    const int x = p & (W - 1);
    const int y = (p >> 8) & (H - 1);

    // query point = grid - flow (flow loaded as one dwordx2)
    const float2 fl = ((const float2*)flow)[p];
    const float qy = (float)y - fl.x;
    const float qx = (float)x - fl.y;

    // floor clamped to [0, size-2]; alpha clipped to [0,1] (tfa semantics)
    const float fy = fminf(fmaxf(floorf(qy), 0.0f), (float)(H - 2));
    const float fx = fminf(fmaxf(floorf(qx), 0.0f), (float)(W - 2));
    const float ay = fminf(fmaxf(qy - fy, 0.0f), 1.0f);
    const float ax = fminf(fmaxf(qx - fx, 0.0f), 1.0f);
    const int iy = (int)fy;
    const int ix = (int)fx;

    const f4* __restrict__ img4 = (const f4*)image;
    // float4-unit index of (b, iy, ix, 4q). (p & ~0xFFFF) == b*H*W.
    const int base = ((p & ~0xFFFF) + (iy << 8) + ix) * QUADS + q;

    const f4 tl0 = img4[base];
    const f4 tr0 = img4[base + QUADS];
    const f4 bl0 = img4[base + R];
    const f4 br0 = img4[base + R + QUADS];
    const f4 tl1 = img4[base + 8];
    const f4 tr1 = img4[base + QUADS + 8];
    const f4 bl1 = img4[base + R + 8];
    const f4 br1 = img4[base + R + QUADS + 8];

    f4 r0, r1;
    #pragma unroll
    for (int e = 0; e < 4; ++e) {
        float top, bot;
        top = fmaf(ax, tr0[e] - tl0[e], tl0[e]);
        bot = fmaf(ax, br0[e] - bl0[e], bl0[e]);
        r0[e] = fmaf(ay, bot - top, top);
        top = fmaf(ax, tr1[e] - tl1[e], tl1[e]);
        bot = fmaf(ax, br1[e] - bl1[e], bl1[e]);
        r1[e] = fmaf(ay, bot - top, top);
    }

    f4* o4 = (f4*)out;
    const int oidx = p * QUADS + q;
    __builtin_nontemporal_store(r0, o4 + oidx);
    __builtin_nontemporal_store(r1, o4 + oidx + 8);
}

extern "C" void kernel_launch(void* const* d_in, const int* in_sizes, int n_in,
                              void* d_out, int out_size, void* d_ws, size_t ws_size,
                              hipStream_t stream) {
    const float* image = (const float*)d_in[0];
    const float* flow  = (const float*)d_in[1];
    float* out = (float*)d_out;

    constexpr int B = 8, H = 256, W = 256;
    const int total_threads = B * H * W * 8;   // 4,194,304 (8 threads/pixel)
    const int block = 256;
    const int grid = total_threads / block;    // 16,384

    warp_bilinear_kernel<<<grid, block, 0, stream>>>(image, flow, out);
}